// Round 10
// baseline (1060.149 us; speedup 1.0000x reference)
//
#include <hip/hip_runtime.h>
#include <stdint.h>

#define DEV __device__ __forceinline__

typedef __bf16 bf16x8 __attribute__((ext_vector_type(8)));
typedef float  f32x4  __attribute__((ext_vector_type(4)));

// ---- model dims ----
// B=128, SEQ=1024, ENC=64, D=512, SEG=64, SNX=16, PRED=512, SNY=8
// N_enc = 8192 rows; N_dec = 65536 rows

DEV unsigned short f2bf(float f){
  union { float f; uint32_t u; } v; v.f = f;
  uint32_t r = (v.u + 0x7FFFu + ((v.u >> 16) & 1u)) >> 16;
  return (unsigned short)r;
}
DEV float bf2f(unsigned short s){
  union { uint32_t u; float f; } v; v.u = ((uint32_t)s) << 16; return v.f;
}
// HW-native transcendentals: v_rcp_f32 + v_exp_f32 (exp2). ~1ulp, bf16 output
// rounding dominates. Avoids exact-division expansion (v_div_* ~10 insts).
DEV float sigm(float x){
  return __builtin_amdgcn_rcpf(1.0f + __builtin_amdgcn_exp2f(-1.442695041f*x));
}
DEV float tanhe(float x){
  return 1.0f - 2.0f*__builtin_amdgcn_rcpf(__builtin_amdgcn_exp2f(2.885390082f*x) + 1.0f);
}

#define AS1(p) ((const __attribute__((address_space(1))) uint32_t*)(p))
#define AS3(p) ((__attribute__((address_space(3))) uint32_t*)(p))

// Stage NROWS x 64 bf16 (row stride ld) into LDS [NROWS][64] via global_load_lds,
// with XOR-swizzled SOURCE: LDS slot t of row r holds global slot t^(r&7).
// Readers XOR their slot with (lane&7). (rule 21 / m173 pattern)
template<int NROWS, int NW>
DEV void gstage(const unsigned short* src, int ld, unsigned short* lds, int tid){
  constexpr int CH = NROWS/8;        // 1KB chunks (8 rows each)
  constexpr int PW = CH/NW;          // chunks per wave
  int wid = tid >> 6, lane = tid & 63;
  int rsub = lane >> 3;              // row within chunk (== row&7)
  int slot = (lane & 7) ^ rsub;      // pre-swizzled global 16B slot
  #pragma unroll
  for (int r = 0; r < PW; r++){
    int chunk = wid*PW + r;
    int row = chunk*8 + rsub;
    __builtin_amdgcn_global_load_lds(AS1(src + (size_t)row*ld + slot*8),
                                     AS3(lds + chunk*512), 16, 0, 0);
  }
}

// ---------- wave tile 32x64 over A[128][64], B[64][64] swizzled LDS ----------
DEV void zero24(f32x4 (&a)[2][4]){
  f32x4 z = {0.f,0.f,0.f,0.f};
  #pragma unroll
  for (int m = 0; m < 2; m++)
    #pragma unroll
    for (int n = 0; n < 4; n++) a[m][n] = z;
}
DEV void zero22(f32x4 (&a)[2][2]){
  f32x4 z = {0.f,0.f,0.f,0.f};
  #pragma unroll
  for (int m = 0; m < 2; m++)
    #pragma unroll
    for (int n = 0; n < 2; n++) a[m][n] = z;
}

DEV void mmaW(const unsigned short* As, const unsigned short* Bs, int wm0,
              int lane, f32x4 (&acc)[2][4]){
  int lr = lane & 15, lk = (lane >> 4)*8, sw = (lane & 7) << 3;
  #pragma unroll
  for (int ks = 0; ks < 2; ks++){
    int ko = (ks*32 + lk) ^ sw;      // row&7 == lane&7 for all rows read
    bf16x8 a[2], b[4];
    #pragma unroll
    for (int m = 0; m < 2; m++)
      a[m] = *reinterpret_cast<const bf16x8*>(&As[(wm0 + m*16 + lr)*64 + ko]);
    #pragma unroll
    for (int n = 0; n < 4; n++)
      b[n] = *reinterpret_cast<const bf16x8*>(&Bs[(n*16 + lr)*64 + ko]);
    #pragma unroll
    for (int m = 0; m < 2; m++)
      #pragma unroll
      for (int n = 0; n < 4; n++)
        acc[m][n] = __builtin_amdgcn_mfma_f32_16x16x32_bf16(a[m], b[n], acc[m][n], 0, 0, 0);
  }
}

// single-acc col-split variant: wave tile 32 rows x 32 cols (B tile 32x64)
DEV void mmaWc(const unsigned short* As, const unsigned short* Bs, int wm0,
               int lane, f32x4 (&acc)[2][2]){
  int lr = lane & 15, lk = (lane >> 4)*8, sw = (lane & 7) << 3;
  #pragma unroll
  for (int ks = 0; ks < 2; ks++){
    int ko = (ks*32 + lk) ^ sw;
    bf16x8 a[2], b[2];
    #pragma unroll
    for (int m = 0; m < 2; m++)
      a[m] = *reinterpret_cast<const bf16x8*>(&As[(wm0 + m*16 + lr)*64 + ko]);
    #pragma unroll
    for (int n = 0; n < 2; n++)
      b[n] = *reinterpret_cast<const bf16x8*>(&Bs[(n*16 + lr)*64 + ko]);
    #pragma unroll
    for (int m = 0; m < 2; m++)
      #pragma unroll
      for (int n = 0; n < 2; n++)
        acc[m][n] = __builtin_amdgcn_mfma_f32_16x16x32_bf16(a[m], b[n], acc[m][n], 0, 0, 0);
  }
}

// col-split 3-gate variant: wave tile 32 rows x 32 cols; B segments of 32 rows
// (Bs + g*2048). A-frags loaded once per ks, reused across 3 gates.
DEV void mmaW3c(const unsigned short* As, const unsigned short* Bs, int wm0,
                int lane, f32x4 (&a1)[2][2], f32x4 (&a2)[2][2], f32x4 (&a3)[2][2]){
  int lr = lane & 15, lk = (lane >> 4)*8, sw = (lane & 7) << 3;
  #pragma unroll
  for (int ks = 0; ks < 2; ks++){
    int ko = (ks*32 + lk) ^ sw;
    bf16x8 a[2], b[2];
    #pragma unroll
    for (int m = 0; m < 2; m++)
      a[m] = *reinterpret_cast<const bf16x8*>(&As[(wm0 + m*16 + lr)*64 + ko]);
    #pragma unroll
    for (int n = 0; n < 2; n++)
      b[n] = *reinterpret_cast<const bf16x8*>(&Bs[(n*16 + lr)*64 + ko]);
    #pragma unroll
    for (int m = 0; m < 2; m++)
      #pragma unroll
      for (int n = 0; n < 2; n++)
        a1[m][n] = __builtin_amdgcn_mfma_f32_16x16x32_bf16(a[m], b[n], a1[m][n], 0, 0, 0);
    #pragma unroll
    for (int n = 0; n < 2; n++)
      b[n] = *reinterpret_cast<const bf16x8*>(&Bs[2048 + (n*16 + lr)*64 + ko]);
    #pragma unroll
    for (int m = 0; m < 2; m++)
      #pragma unroll
      for (int n = 0; n < 2; n++)
        a2[m][n] = __builtin_amdgcn_mfma_f32_16x16x32_bf16(a[m], b[n], a2[m][n], 0, 0, 0);
    #pragma unroll
    for (int n = 0; n < 2; n++)
      b[n] = *reinterpret_cast<const bf16x8*>(&Bs[4096 + (n*16 + lr)*64 + ko]);
    #pragma unroll
    for (int m = 0; m < 2; m++)
      #pragma unroll
      for (int n = 0; n < 2; n++)
        a3[m][n] = __builtin_amdgcn_mfma_f32_16x16x32_bf16(a[m], b[n], a3[m][n], 0, 0, 0);
  }
}

// Single-buffered K=512 loop: A 128 rows, B 64 rows, both ld=512. 24KB LDS.
DEV void kloopS(const unsigned short* A0, const unsigned short* B0,
                unsigned short* As, unsigned short* Bs,
                int tid, int wm0, int lane, f32x4 (&acc)[2][4]){
  for (int kt = 0; kt < 8; kt++){
    gstage<128,4>(A0 + kt*64, 512, As, tid);
    gstage<64,4>(B0 + kt*64, 512, Bs, tid);
    __syncthreads();
    mmaW(As, Bs, wm0, lane, acc);
    __syncthreads();
  }
}

// ---------------- one-shot prep kernels ----------------
__global__ __launch_bounds__(256) void cvt_all_kernel(
    const float* cWih, const float* cWhh, const float* gWih, const float* gWhh,
    const float* resW, const float* predW, const float* Wemb,
    unsigned short* o0, unsigned short* o1, unsigned short* o2, unsigned short* o3,
    unsigned short* o4, unsigned short* o5, unsigned short* o6){
  int g = blockIdx.x*256 + threadIdx.x;   // group of 4 f32
  const float* s; unsigned short* d; int idx;
  if      (g < 196608){ s=cWih;  d=o0; idx=g; }
  else if (g < 393216){ s=cWhh;  d=o1; idx=g-196608; }
  else if (g < 589824){ s=gWih;  d=o2; idx=g-393216; }
  else if (g < 786432){ s=gWhh;  d=o3; idx=g-589824; }
  else if (g < 851968){ s=resW;  d=o4; idx=g-786432; }
  else if (g < 860160){ s=predW; d=o5; idx=g-851968; }
  else if (g < 868352){ s=Wemb;  d=o6; idx=g-860160; }
  else return;
  float4 v = reinterpret_cast<const float4*>(s)[idx];
  ushort4 r; r.x=f2bf(v.x); r.y=f2bf(v.y); r.z=f2bf(v.z); r.w=f2bf(v.w);
  reinterpret_cast<ushort4*>(d)[idx] = r;
}

__global__ __launch_bounds__(256) void build_pe_kernel(const float* pos, const float* chan, unsigned short* pe){
  int i = blockIdx.x*256 + threadIdx.x;   // 262144 total
  if (i >= 512*512) return;
  int m = i >> 9, d = i & 511;
  int c = m >> 3, sy = m & 7;
  float v = (d < 256) ? pos[sy*256 + d] : chan[c*256 + (d-256)];
  pe[i] = f2bf(v);
}

// xs_all[n][tk] = bf16(x[b,tk,c] - x[b,1023,c]),  n = b*64+c.  Transpose via LDS.
__global__ __launch_bounds__(256) void xs_kernel(const float* __restrict__ x,
                                                 unsigned short* __restrict__ xs){
  __shared__ float tile[64][65];
  __shared__ float lastv[64];
  int b = blockIdx.y, tk0 = blockIdx.x*64, tid = threadIdx.x;
  if (tid < 64) lastv[tid] = x[(size_t)b*65536 + 65472 + tid];
  #pragma unroll
  for (int k = 0; k < 16; k++){
    int id = tid + k*256;
    int i = id >> 6, c = id & 63;
    tile[i][c] = x[(size_t)b*65536 + (size_t)(tk0+i)*64 + c];
  }
  __syncthreads();
  #pragma unroll
  for (int k = 0; k < 16; k++){
    int id = tid + k*256;
    int c = id >> 6, i = id & 63;
    xs[(size_t)(b*64 + c)*1024 + tk0 + i] = f2bf(tile[i][c] - lastv[c]);
  }
}

// ---------------- embedding GEMM: emb = silu(xs_t @ Wemb^T + b), K=64 ----------------
__global__ __launch_bounds__(256) void embed_kernel(const unsigned short* __restrict__ xs,
    const unsigned short* __restrict__ wemb, const float* __restrict__ bemb,
    unsigned short* __restrict__ embout, int t0, size_t zs){
  __shared__ unsigned short As[8192];
  __shared__ unsigned short Bs[4096];
  int tid = threadIdx.x, lane = tid & 63, wid = tid >> 6, wm0 = wid*32;
  int rA0 = blockIdx.x*128, d0 = blockIdx.y*64;
  int t = t0 + blockIdx.z;
  unsigned short* out = embout + (size_t)blockIdx.z * zs;

  gstage<128,4>(xs + (size_t)rA0*1024 + t*64, 1024, As, tid);
  gstage<64,4>(wemb + (size_t)d0*64, 64, Bs, tid);
  __syncthreads();
  f32x4 acc[2][4]; zero24(acc);
  mmaW(As, Bs, wm0, lane, acc);

  int lr = lane & 15, lj = (lane >> 4)*4;
  #pragma unroll
  for (int m = 0; m < 2; m++)
    #pragma unroll
    for (int n = 0; n < 4; n++){
      int col = d0 + n*16 + lr;
      float bb = bemb[col];
      #pragma unroll
      for (int j = 0; j < 4; j++){
        int row = rA0 + wm0 + m*16 + lj + j;
        float v = acc[m][n][j] + bb;
        v = v * sigm(v);
        out[(size_t)row*512 + col] = f2bf(v);
      }
    }
}

// ---------------- encoder gates -> h_cell (col-split 128x32, XCD-grouped) ----------------
// Flat grid 1024. Decode so all 16 col-blocks of a row-group land on ONE XCD
// (XCD = id%8 round-robin): g = (id&7) + 8*(id>>7), c = (id>>3)&15.
// LDS 28KB -> 5 blocks/CU with __launch_bounds__(256,5) (round-9 lesson: declare it).
__global__ __launch_bounds__(256,5) void gates_kernel(
    const unsigned short* __restrict__ emb, const unsigned short* __restrict__ hbf,
    const unsigned short* __restrict__ Wih, const unsigned short* __restrict__ Whh,
    const float* __restrict__ bih, const float* __restrict__ bhh,
    unsigned short* __restrict__ hcell){
  __shared__ unsigned short As[8192];       // 128x64 A tile (16KB)
  __shared__ unsigned short Bs[3*2048];     // 3 x 32x64 B tiles (12KB)
  int tid = threadIdx.x, lane = tid & 63, wid = tid >> 6, wm0 = wid*32;
  int id = blockIdx.x;
  int g = (id & 7) + ((id >> 7) << 3);      // row-group 0..63 (8 per XCD)
  int c = (id >> 3) & 15;                   // col-block 0..15
  int rA0 = g*128, d0 = c*32;

  f32x4 aR[2][2], aZ[2][2], aNx[2][2], aNh[2][2];
  zero22(aR); zero22(aZ); zero22(aNx); zero22(aNh);

  // pass E: A = emb, B = Wih{R,Z,N}
  {
    const unsigned short* A = emb + (size_t)rA0*512;
    const unsigned short* BR = Wih + (size_t)d0*512;
    const unsigned short* BZ = Wih + (size_t)(512 + d0)*512;
    const unsigned short* BN = Wih + (size_t)(1024 + d0)*512;
    for (int kt = 0; kt < 8; kt++){
      gstage<128,4>(A + kt*64, 512, As, tid);
      gstage<32,4>(BR + kt*64, 512, Bs, tid);
      gstage<32,4>(BZ + kt*64, 512, Bs + 2048, tid);
      gstage<32,4>(BN + kt*64, 512, Bs + 4096, tid);
      __syncthreads();
      mmaW3c(As, Bs, wm0, lane, aR, aZ, aNx);
      __syncthreads();
    }
  }
  // pass H: A = h, B = Whh{R,Z,N}
  {
    const unsigned short* A = hbf + (size_t)rA0*512;
    const unsigned short* BR = Whh + (size_t)d0*512;
    const unsigned short* BZ = Whh + (size_t)(512 + d0)*512;
    const unsigned short* BN = Whh + (size_t)(1024 + d0)*512;
    for (int kt = 0; kt < 8; kt++){
      gstage<128,4>(A + kt*64, 512, As, tid);
      gstage<32,4>(BR + kt*64, 512, Bs, tid);
      gstage<32,4>(BZ + kt*64, 512, Bs + 2048, tid);
      gstage<32,4>(BN + kt*64, 512, Bs + 4096, tid);
      __syncthreads();
      mmaW3c(As, Bs, wm0, lane, aR, aZ, aNh);
      __syncthreads();
    }
  }

  int lr = lane & 15, lj = (lane >> 4)*4;
  #pragma unroll
  for (int n = 0; n < 2; n++){
    int col = d0 + n*16 + lr;
    float brr = bih[col] + bhh[col];
    float bzz = bih[512 + col] + bhh[512 + col];
    float bni = bih[1024 + col], bnh = bhh[1024 + col];
    #pragma unroll
    for (int m = 0; m < 2; m++)
      #pragma unroll
      for (int j = 0; j < 4; j++){
        int row = rA0 + wm0 + m*16 + lj + j;
        float rg = sigm(aR[m][n][j] + brr);
        float zg = sigm(aZ[m][n][j] + bzz);
        float ng = tanhe(aNx[m][n][j] + bni + rg*(aNh[m][n][j] + bnh));
        float h  = bf2f(hbf[(size_t)row*512 + col]);
        hcell[(size_t)row*512 + col] = f2bf((1.0f - zg)*ng + zg*h);
      }
  }
}

// ---------------- residual projection (col-split 128x32, XCD-grouped) ----------------
// h_new = emb + h_cell @ res_W^T + res_b. LDS 20KB -> 7 blocks/CU declared.
__global__ __launch_bounds__(256,7) void res_kernel(
    const unsigned short* __restrict__ hcell, const unsigned short* __restrict__ Wres,
    const float* __restrict__ res_b, const unsigned short* __restrict__ emb,
    unsigned short* __restrict__ hbf){
  __shared__ unsigned short As[8192];   // 128x64 A tile (16KB)
  __shared__ unsigned short Bs[2048];   // 32x64 B tile (4KB)
  int tid = threadIdx.x, lane = tid & 63, wid = tid >> 6, wm0 = wid*32;
  int id = blockIdx.x;
  int g = (id & 7) + ((id >> 7) << 3);  // row-group 0..63
  int c = (id >> 3) & 15;               // col-block 0..15
  int rA0 = g*128, d0 = c*32;

  f32x4 acc[2][2]; zero22(acc);
  const unsigned short* A = hcell + (size_t)rA0*512;
  const unsigned short* Bw = Wres + (size_t)d0*512;
  for (int kt = 0; kt < 8; kt++){
    gstage<128,4>(A + kt*64, 512, As, tid);
    gstage<32,4>(Bw + kt*64, 512, Bs, tid);
    __syncthreads();
    mmaWc(As, Bs, wm0, lane, acc);
    __syncthreads();
  }

  int lr = lane & 15, lj = (lane >> 4)*4;
  #pragma unroll
  for (int n = 0; n < 2; n++){
    int col = d0 + n*16 + lr;
    float bb = res_b[col];
    #pragma unroll
    for (int m = 0; m < 2; m++)
      #pragma unroll
      for (int j = 0; j < 4; j++){
        int row = rA0 + wm0 + m*16 + lj + j;
        float v = acc[m][n][j] + bb + bf2f(emb[(size_t)row*512 + col]);
        hbf[(size_t)row*512 + col] = f2bf(v);
      }
  }
}

// ---------------- generic: C = A(Mx512) @ B^T + bias, out ld=Nld ----------------
template<bool BF16OUT>
__global__ __launch_bounds__(256) void gemm_bias_kernel(
    const unsigned short* __restrict__ A, const unsigned short* __restrict__ B,
    const float* __restrict__ bias, float* __restrict__ Cf,
    unsigned short* __restrict__ Cb, int Nld){
  __shared__ unsigned short As[8192];
  __shared__ unsigned short Bs[4096];
  int tid = threadIdx.x, lane = tid & 63, wid = tid >> 6, wm0 = wid*32;
  int rA0 = blockIdx.x*128, rB0 = blockIdx.y*64;

  f32x4 acc[2][4]; zero24(acc);
  kloopS(A + (size_t)rA0*512, B + (size_t)rB0*512, As, Bs, tid, wm0, lane, acc);

  int lr = lane & 15, lj = (lane >> 4)*4;
  #pragma unroll
  for (int m = 0; m < 2; m++)
    #pragma unroll
    for (int n = 0; n < 4; n++){
      int col = rB0 + n*16 + lr;
      float bb = bias[col];
      #pragma unroll
      for (int j = 0; j < 4; j++){
        int row = rA0 + wm0 + m*16 + lj + j;
        float v = acc[m][n][j] + bb;
        if (BF16OUT) Cb[(size_t)row*Nld + col] = f2bf(v);
        else         Cf[(size_t)row*Nld + col] = v;
      }
    }
}

// ---------------- bf16x8 unpack: 1 VALU per value ----------------
DEV void bf8ld(const unsigned short* p, float* o){
  uint4 u = *reinterpret_cast<const uint4*>(p);
  union { uint32_t w; float f; } v;
  v.w = u.x << 16;          o[0] = v.f;
  v.w = u.x & 0xffff0000u;  o[1] = v.f;
  v.w = u.y << 16;          o[2] = v.f;
  v.w = u.y & 0xffff0000u;  o[3] = v.f;
  v.w = u.z << 16;          o[4] = v.f;
  v.w = u.z & 0xffff0000u;  o[5] = v.f;
  v.w = u.w << 16;          o[6] = v.f;
  v.w = u.w & 0xffff0000u;  o[7] = v.f;
}

// ---------------- fused decoder: hy built in-kernel -> predict GEMM -> out ----------------
// Kills the 67MB hy round-trip + one launch. Per k-tile: 256 threads build the
// 128x64 hy sub-tile (2 threads/row, 4x 8-elem slots each) and ds_write it
// XOR-swizzled (slot ^ (row&7)) so mmaW's swizzled reads see a linear tile.
__global__ __launch_bounds__(256) void pred_fused_kernel(
    const float* __restrict__ gxd, const unsigned short* __restrict__ ghd,
    const unsigned short* __restrict__ hb, const unsigned short* __restrict__ predW,
    const float* __restrict__ predb, const float* __restrict__ x,
    float* __restrict__ out){
  __shared__ unsigned short As[8192];   // 128x64 hy tile (16KB, swizzled)
  __shared__ unsigned short Bs[4096];   // 64x64 predW tile (8KB, gstage-swizzled)
  int tid = threadIdx.x, lane = tid & 63, wid = tid >> 6, wm0 = wid*32;
  int rA0 = blockIdx.x*128;

  // per-thread fixed row for the hy build
  int rl = tid >> 1, q = tid & 1;
  int r = rA0 + rl;
  int nn = r >> 3, sy = r & 7, cc = nn & 63, mpe = cc*8 + sy;
  (void)sy;
  const float* gx = gxd + (size_t)mpe*1536;
  const unsigned short* gh = ghd + (size_t)nn*1536;
  const unsigned short* hh = hb + (size_t)nn*512;

  f32x4 acc[2][4]; zero24(acc);

  for (int kt = 0; kt < 8; kt++){
    #pragma unroll
    for (int s = 0; s < 4; s++){
      int dq = kt*64 + q*32 + s*8;
      float4 xa = *reinterpret_cast<const float4*>(gx + dq);
      float4 xb = *reinterpret_cast<const float4*>(gx + dq + 4);
      float4 za = *reinterpret_cast<const float4*>(gx + 512 + dq);
      float4 zb = *reinterpret_cast<const float4*>(gx + 516 + dq);
      float4 na = *reinterpret_cast<const float4*>(gx + 1024 + dq);
      float4 nb = *reinterpret_cast<const float4*>(gx + 1028 + dq);
      float xr[8] = {xa.x,xa.y,xa.z,xa.w,xb.x,xb.y,xb.z,xb.w};
      float xz[8] = {za.x,za.y,za.z,za.w,zb.x,zb.y,zb.z,zb.w};
      float xn[8] = {na.x,na.y,na.z,na.w,nb.x,nb.y,nb.z,nb.w};
      float hr[8], hz[8], hn[8], h[8];
      bf8ld(gh + dq, hr); bf8ld(gh + 512 + dq, hz);
      bf8ld(gh + 1024 + dq, hn); bf8ld(hh + dq, h);
      unsigned short w[8];
      #pragma unroll
      for (int j = 0; j < 8; j++){
        float rg = sigm(xr[j] + hr[j]);
        float zg = sigm(xz[j] + hz[j]);
        float ng = tanhe(xn[j] + rg*hn[j]);
        w[j] = f2bf((1.0f - zg)*ng + zg*h[j]);
      }
      int slot = (q*4 + s) ^ (rl & 7);
      *reinterpret_cast<uint4*>(&As[rl*64 + slot*8]) =
          *reinterpret_cast<const uint4*>(w);
    }
    gstage<64,4>(predW + kt*64, 512, Bs, tid);
    __syncthreads();
    mmaW(As, Bs, wm0, lane, acc);
    __syncthreads();
  }

  int lr = lane & 15, lj = (lane >> 4)*4;
  #pragma unroll
  for (int n = 0; n < 4; n++){
    int s = n*16 + lr;
    float bb = predb[s];
    #pragma unroll
    for (int m = 0; m < 2; m++)
      #pragma unroll
      for (int j = 0; j < 4; j++){
        int rr = rA0 + wm0 + m*16 + lj + j;
        int n2 = rr >> 3, sy2 = rr & 7, b = n2 >> 6, c2 = n2 & 63;
        out[(size_t)b*32768 + (size_t)(sy2*64 + s)*64 + c2] =
            acc[m][n][j] + bb + x[(size_t)b*65536 + 65472 + c2];
      }
  }
}

// ---------------- host ----------------
extern "C" void kernel_launch(void* const* d_in, const int* in_sizes, int n_in,
                              void* d_out, int out_size, void* d_ws, size_t ws_size,
                              hipStream_t stream){
  (void)in_sizes; (void)n_in; (void)out_size;
  const float* x     = (const float*)d_in[0];
  const float* Wemb  = (const float*)d_in[1];
  const float* bemb  = (const float*)d_in[2];
  const float* cWih  = (const float*)d_in[3];
  const float* cWhh  = (const float*)d_in[4];
  const float* cbih  = (const float*)d_in[5];
  const float* cbhh  = (const float*)d_in[6];
  const float* gWih  = (const float*)d_in[7];
  const float* gWhh  = (const float*)d_in[8];
  const float* gbih  = (const float*)d_in[9];
  const float* gbhh  = (const float*)d_in[10];
  const float* resW  = (const float*)d_in[11];
  const float* resb  = (const float*)d_in[12];
  const float* pos   = (const float*)d_in[13];
  const float* chan  = (const float*)d_in[14];
  const float* predW = (const float*)d_in[15];
  const float* predb = (const float*)d_in[16];
  float* out = (float*)d_out;

  uint8_t* ws = (uint8_t*)d_ws;
  size_t o = 0;
  auto take = [&](size_t bytes){ uint8_t* p = ws + o; o += (bytes + 255) & ~(size_t)255; return p; };
  unsigned short* wb_cWih  = (unsigned short*)take(786432*2);
  unsigned short* wb_cWhh  = (unsigned short*)take(786432*2);
  unsigned short* wb_gWih  = (unsigned short*)take(786432*2);
  unsigned short* wb_gWhh  = (unsigned short*)take(786432*2);
  unsigned short* wb_resW  = (unsigned short*)take(262144*2);
  unsigned short* wb_predW = (unsigned short*)take(32768*2);
  unsigned short* wb_Wemb  = (unsigned short*)take(32768*2);
  unsigned short* pe_bf    = (unsigned short*)take(262144*2);
  unsigned short* h_bf     = (unsigned short*)take(4194304*2);

  // union region: encoder {xs_all, hcell, emb} / decoder {ghd(bf16), gxd(f32)}
  uint8_t* U = ws + o;
  unsigned short* xs_all = (unsigned short*)(U);
  unsigned short* hcell  = (unsigned short*)(U + 16777216);
  unsigned short* emb    = (unsigned short*)(U + 25165824);
  unsigned short* ghd    = (unsigned short*)(U);                 // 8192*1536*2 = 25165824
  float*          gxd    = (float*)(U + 25165824);               // 512*1536*4  = 3145728

  bool big = ws_size >= o + (size_t)25165824 + (size_t)16*8388608;
  size_t zs = big ? 4194304 : 0;

  cvt_all_kernel<<<3392, 256, 0, stream>>>(cWih, cWhh, gWih, gWhh, resW, predW, Wemb,
      wb_cWih, wb_cWhh, wb_gWih, wb_gWhh, wb_resW, wb_predW, wb_Wemb);
  build_pe_kernel<<<1024, 256, 0, stream>>>(pos, chan, pe_bf);
  xs_kernel<<<dim3(16, 128), 256, 0, stream>>>(x, xs_all);
  hipMemsetAsync(h_bf, 0, (size_t)4194304*2, stream);

  if (big)
    embed_kernel<<<dim3(64, 8, 16), 256, 0, stream>>>(xs_all, wb_Wemb, bemb, emb, 0, zs);

  for (int t = 0; t < 16; t++){
    const unsigned short* emb_t = emb + (big ? (size_t)t*4194304 : 0);
    if (!big)
      embed_kernel<<<dim3(64, 8, 1), 256, 0, stream>>>(xs_all, wb_Wemb, bemb,
                                                       (unsigned short*)emb_t, t, 0);
    gates_kernel<<<1024, 256, 0, stream>>>(emb_t, h_bf, wb_cWih, wb_cWhh,
                                           cbih, cbhh, hcell);
    res_kernel<<<1024, 256, 0, stream>>>(hcell, wb_resW, resb, emb_t, h_bf);
  }

  // decoder: ghd(bf16) = hn @ gru_Whh^T + gbhh ; gxd(f32) = pe @ gru_Wih^T + gbih
  gemm_bias_kernel<true><<<dim3(64, 24), 256, 0, stream>>>(h_bf, wb_gWhh, gbhh,
                                                           nullptr, ghd, 1536);
  gemm_bias_kernel<false><<<dim3(4, 24), 256, 0, stream>>>(pe_bf, wb_gWih, gbih,
                                                           gxd, nullptr, 1536);
  pred_fused_kernel<<<512, 256, 0, stream>>>(gxd, ghd, h_bf, wb_predW, predb, x, out);
}

// Round 11
// 742.322 us; speedup vs baseline: 1.4282x; 1.4282x over previous
//
#include <hip/hip_runtime.h>
#include <stdint.h>

#define DEV __device__ __forceinline__

typedef __bf16 bf16x8 __attribute__((ext_vector_type(8)));
typedef float  f32x4  __attribute__((ext_vector_type(4)));

// ---- model dims ----
// B=128, SEQ=1024, ENC=64, D=512, SEG=64, SNX=16, PRED=512, SNY=8
// N_enc = 8192 rows; N_dec = 65536 rows

DEV unsigned short f2bf(float f){
  union { float f; uint32_t u; } v; v.f = f;
  uint32_t r = (v.u + 0x7FFFu + ((v.u >> 16) & 1u)) >> 16;
  return (unsigned short)r;
}
DEV float bf2f(unsigned short s){
  union { uint32_t u; float f; } v; v.u = ((uint32_t)s) << 16; return v.f;
}
// HW-native transcendentals: v_rcp_f32 + v_exp_f32 (exp2). ~1ulp, bf16 output
// rounding dominates. Avoids exact-division expansion (v_div_* ~10 insts).
DEV float sigm(float x){
  return __builtin_amdgcn_rcpf(1.0f + __builtin_amdgcn_exp2f(-1.442695041f*x));
}
DEV float tanhe(float x){
  return 1.0f - 2.0f*__builtin_amdgcn_rcpf(__builtin_amdgcn_exp2f(2.885390082f*x) + 1.0f);
}

#define AS1(p) ((const __attribute__((address_space(1))) uint32_t*)(p))
#define AS3(p) ((__attribute__((address_space(3))) uint32_t*)(p))

// Stage NROWS x 64 bf16 (row stride ld) into LDS [NROWS][64] via global_load_lds,
// with XOR-swizzled SOURCE: LDS slot t of row r holds global slot t^(r&7).
// Readers XOR their slot with (lane&7). (rule 21 / m173 pattern)
template<int NROWS, int NW>
DEV void gstage(const unsigned short* src, int ld, unsigned short* lds, int tid){
  constexpr int CH = NROWS/8;        // 1KB chunks (8 rows each)
  constexpr int PW = CH/NW;          // chunks per wave
  int wid = tid >> 6, lane = tid & 63;
  int rsub = lane >> 3;              // row within chunk (== row&7)
  int slot = (lane & 7) ^ rsub;      // pre-swizzled global 16B slot
  #pragma unroll
  for (int r = 0; r < PW; r++){
    int chunk = wid*PW + r;
    int row = chunk*8 + rsub;
    __builtin_amdgcn_global_load_lds(AS1(src + (size_t)row*ld + slot*8),
                                     AS3(lds + chunk*512), 16, 0, 0);
  }
}

// ---------- wave tile 32x64 over A[128][64], B[64][64] swizzled LDS ----------
DEV void zero24(f32x4 (&a)[2][4]){
  f32x4 z = {0.f,0.f,0.f,0.f};
  #pragma unroll
  for (int m = 0; m < 2; m++)
    #pragma unroll
    for (int n = 0; n < 4; n++) a[m][n] = z;
}
DEV void zero22(f32x4 (&a)[2][2]){
  f32x4 z = {0.f,0.f,0.f,0.f};
  #pragma unroll
  for (int m = 0; m < 2; m++)
    #pragma unroll
    for (int n = 0; n < 2; n++) a[m][n] = z;
}

DEV void mmaW(const unsigned short* As, const unsigned short* Bs, int wm0,
              int lane, f32x4 (&acc)[2][4]){
  int lr = lane & 15, lk = (lane >> 4)*8, sw = (lane & 7) << 3;
  #pragma unroll
  for (int ks = 0; ks < 2; ks++){
    int ko = (ks*32 + lk) ^ sw;      // row&7 == lane&7 for all rows read
    bf16x8 a[2], b[4];
    #pragma unroll
    for (int m = 0; m < 2; m++)
      a[m] = *reinterpret_cast<const bf16x8*>(&As[(wm0 + m*16 + lr)*64 + ko]);
    #pragma unroll
    for (int n = 0; n < 4; n++)
      b[n] = *reinterpret_cast<const bf16x8*>(&Bs[(n*16 + lr)*64 + ko]);
    #pragma unroll
    for (int m = 0; m < 2; m++)
      #pragma unroll
      for (int n = 0; n < 4; n++)
        acc[m][n] = __builtin_amdgcn_mfma_f32_16x16x32_bf16(a[m], b[n], acc[m][n], 0, 0, 0);
  }
}

// col-split 3-gate variant: wave tile 32 rows x 32 cols; B segments of 32 rows
// (Bs + g*2048). A-frags loaded once per ks, reused across 3 gates.
DEV void mmaW3c(const unsigned short* As, const unsigned short* Bs, int wm0,
                int lane, f32x4 (&a1)[2][2], f32x4 (&a2)[2][2], f32x4 (&a3)[2][2]){
  int lr = lane & 15, lk = (lane >> 4)*8, sw = (lane & 7) << 3;
  #pragma unroll
  for (int ks = 0; ks < 2; ks++){
    int ko = (ks*32 + lk) ^ sw;
    bf16x8 a[2], b[2];
    #pragma unroll
    for (int m = 0; m < 2; m++)
      a[m] = *reinterpret_cast<const bf16x8*>(&As[(wm0 + m*16 + lr)*64 + ko]);
    #pragma unroll
    for (int n = 0; n < 2; n++)
      b[n] = *reinterpret_cast<const bf16x8*>(&Bs[(n*16 + lr)*64 + ko]);
    #pragma unroll
    for (int m = 0; m < 2; m++)
      #pragma unroll
      for (int n = 0; n < 2; n++)
        a1[m][n] = __builtin_amdgcn_mfma_f32_16x16x32_bf16(a[m], b[n], a1[m][n], 0, 0, 0);
    #pragma unroll
    for (int n = 0; n < 2; n++)
      b[n] = *reinterpret_cast<const bf16x8*>(&Bs[2048 + (n*16 + lr)*64 + ko]);
    #pragma unroll
    for (int m = 0; m < 2; m++)
      #pragma unroll
      for (int n = 0; n < 2; n++)
        a2[m][n] = __builtin_amdgcn_mfma_f32_16x16x32_bf16(a[m], b[n], a2[m][n], 0, 0, 0);
    #pragma unroll
    for (int n = 0; n < 2; n++)
      b[n] = *reinterpret_cast<const bf16x8*>(&Bs[4096 + (n*16 + lr)*64 + ko]);
    #pragma unroll
    for (int m = 0; m < 2; m++)
      #pragma unroll
      for (int n = 0; n < 2; n++)
        a3[m][n] = __builtin_amdgcn_mfma_f32_16x16x32_bf16(a[m], b[n], a3[m][n], 0, 0, 0);
  }
}

// Single-buffered K=512 loop: A 128 rows, B 64 rows, both ld=512. 24KB LDS.
DEV void kloopS(const unsigned short* A0, const unsigned short* B0,
                unsigned short* As, unsigned short* Bs,
                int tid, int wm0, int lane, f32x4 (&acc)[2][4]){
  for (int kt = 0; kt < 8; kt++){
    gstage<128,4>(A0 + kt*64, 512, As, tid);
    gstage<64,4>(B0 + kt*64, 512, Bs, tid);
    __syncthreads();
    mmaW(As, Bs, wm0, lane, acc);
    __syncthreads();
  }
}

// ---------------- one-shot prep kernels ----------------
__global__ __launch_bounds__(256) void cvt_all_kernel(
    const float* cWih, const float* cWhh, const float* gWih, const float* gWhh,
    const float* resW, const float* predW, const float* Wemb,
    unsigned short* o0, unsigned short* o1, unsigned short* o2, unsigned short* o3,
    unsigned short* o4, unsigned short* o5, unsigned short* o6){
  int g = blockIdx.x*256 + threadIdx.x;   // group of 4 f32
  const float* s; unsigned short* d; int idx;
  if      (g < 196608){ s=cWih;  d=o0; idx=g; }
  else if (g < 393216){ s=cWhh;  d=o1; idx=g-196608; }
  else if (g < 589824){ s=gWih;  d=o2; idx=g-393216; }
  else if (g < 786432){ s=gWhh;  d=o3; idx=g-589824; }
  else if (g < 851968){ s=resW;  d=o4; idx=g-786432; }
  else if (g < 860160){ s=predW; d=o5; idx=g-851968; }
  else if (g < 868352){ s=Wemb;  d=o6; idx=g-860160; }
  else return;
  float4 v = reinterpret_cast<const float4*>(s)[idx];
  ushort4 r; r.x=f2bf(v.x); r.y=f2bf(v.y); r.z=f2bf(v.z); r.w=f2bf(v.w);
  reinterpret_cast<ushort4*>(d)[idx] = r;
}

__global__ __launch_bounds__(256) void build_pe_kernel(const float* pos, const float* chan, unsigned short* pe){
  int i = blockIdx.x*256 + threadIdx.x;   // 262144 total
  if (i >= 512*512) return;
  int m = i >> 9, d = i & 511;
  int c = m >> 3, sy = m & 7;
  float v = (d < 256) ? pos[sy*256 + d] : chan[c*256 + (d-256)];
  pe[i] = f2bf(v);
}

// xs_all[n][tk] = bf16(x[b,tk,c] - x[b,1023,c]),  n = b*64+c.  Transpose via LDS.
__global__ __launch_bounds__(256) void xs_kernel(const float* __restrict__ x,
                                                 unsigned short* __restrict__ xs){
  __shared__ float tile[64][65];
  __shared__ float lastv[64];
  int b = blockIdx.y, tk0 = blockIdx.x*64, tid = threadIdx.x;
  if (tid < 64) lastv[tid] = x[(size_t)b*65536 + 65472 + tid];
  #pragma unroll
  for (int k = 0; k < 16; k++){
    int id = tid + k*256;
    int i = id >> 6, c = id & 63;
    tile[i][c] = x[(size_t)b*65536 + (size_t)(tk0+i)*64 + c];
  }
  __syncthreads();
  #pragma unroll
  for (int k = 0; k < 16; k++){
    int id = tid + k*256;
    int c = id >> 6, i = id & 63;
    xs[(size_t)(b*64 + c)*1024 + tk0 + i] = f2bf(tile[i][c] - lastv[c]);
  }
}

// ---------------- embedding GEMM: emb = silu(xs_t @ Wemb^T + b), K=64 ----------------
__global__ __launch_bounds__(256) void embed_kernel(const unsigned short* __restrict__ xs,
    const unsigned short* __restrict__ wemb, const float* __restrict__ bemb,
    unsigned short* __restrict__ embout, int t0, size_t zs){
  __shared__ unsigned short As[8192];
  __shared__ unsigned short Bs[4096];
  int tid = threadIdx.x, lane = tid & 63, wid = tid >> 6, wm0 = wid*32;
  int rA0 = blockIdx.x*128, d0 = blockIdx.y*64;
  int t = t0 + blockIdx.z;
  unsigned short* out = embout + (size_t)blockIdx.z * zs;

  gstage<128,4>(xs + (size_t)rA0*1024 + t*64, 1024, As, tid);
  gstage<64,4>(wemb + (size_t)d0*64, 64, Bs, tid);
  __syncthreads();
  f32x4 acc[2][4]; zero24(acc);
  mmaW(As, Bs, wm0, lane, acc);

  int lr = lane & 15, lj = (lane >> 4)*4;
  #pragma unroll
  for (int m = 0; m < 2; m++)
    #pragma unroll
    for (int n = 0; n < 4; n++){
      int col = d0 + n*16 + lr;
      float bb = bemb[col];
      #pragma unroll
      for (int j = 0; j < 4; j++){
        int row = rA0 + wm0 + m*16 + lj + j;
        float v = acc[m][n][j] + bb;
        v = v * sigm(v);
        out[(size_t)row*512 + col] = f2bf(v);
      }
    }
}

// ---------------- encoder gates -> h_cell (col-split 128x32, XCD-grouped) ----------------
// Flat grid 1024. Decode so all 16 col-blocks of a row-group land on ONE XCD
// (XCD = id%8 round-robin): g = (id&7) + 8*(id>>7), c = (id>>3)&15.
// A/h tile then fetched once per row-group into that XCD's L2 (round-6 evidence:
// same-XCD grouping measured FETCH 26 MB vs 82 MB when spread).
__global__ __launch_bounds__(256,4) void gates_kernel(
    const unsigned short* __restrict__ emb, const unsigned short* __restrict__ hbf,
    const unsigned short* __restrict__ Wih, const unsigned short* __restrict__ Whh,
    const float* __restrict__ bih, const float* __restrict__ bhh,
    unsigned short* __restrict__ hcell){
  __shared__ unsigned short As[8192];       // 128x64 A tile (16KB)
  __shared__ unsigned short Bs[3*2048];     // 3 x 32x64 B tiles (12KB)
  int tid = threadIdx.x, lane = tid & 63, wid = tid >> 6, wm0 = wid*32;
  int id = blockIdx.x;
  int g = (id & 7) + ((id >> 7) << 3);      // row-group 0..63 (8 per XCD)
  int c = (id >> 3) & 15;                   // col-block 0..15
  int rA0 = g*128, d0 = c*32;

  f32x4 aR[2][2], aZ[2][2], aNx[2][2], aNh[2][2];
  zero22(aR); zero22(aZ); zero22(aNx); zero22(aNh);

  // pass E: A = emb, B = Wih{R,Z,N}
  {
    const unsigned short* A = emb + (size_t)rA0*512;
    const unsigned short* BR = Wih + (size_t)d0*512;
    const unsigned short* BZ = Wih + (size_t)(512 + d0)*512;
    const unsigned short* BN = Wih + (size_t)(1024 + d0)*512;
    for (int kt = 0; kt < 8; kt++){
      gstage<128,4>(A + kt*64, 512, As, tid);
      gstage<32,4>(BR + kt*64, 512, Bs, tid);
      gstage<32,4>(BZ + kt*64, 512, Bs + 2048, tid);
      gstage<32,4>(BN + kt*64, 512, Bs + 4096, tid);
      __syncthreads();
      mmaW3c(As, Bs, wm0, lane, aR, aZ, aNx);
      __syncthreads();
    }
  }
  // pass H: A = h, B = Whh{R,Z,N}
  {
    const unsigned short* A = hbf + (size_t)rA0*512;
    const unsigned short* BR = Whh + (size_t)d0*512;
    const unsigned short* BZ = Whh + (size_t)(512 + d0)*512;
    const unsigned short* BN = Whh + (size_t)(1024 + d0)*512;
    for (int kt = 0; kt < 8; kt++){
      gstage<128,4>(A + kt*64, 512, As, tid);
      gstage<32,4>(BR + kt*64, 512, Bs, tid);
      gstage<32,4>(BZ + kt*64, 512, Bs + 2048, tid);
      gstage<32,4>(BN + kt*64, 512, Bs + 4096, tid);
      __syncthreads();
      mmaW3c(As, Bs, wm0, lane, aR, aZ, aNh);
      __syncthreads();
    }
  }

  int lr = lane & 15, lj = (lane >> 4)*4;
  #pragma unroll
  for (int n = 0; n < 2; n++){
    int col = d0 + n*16 + lr;
    float brr = bih[col] + bhh[col];
    float bzz = bih[512 + col] + bhh[512 + col];
    float bni = bih[1024 + col], bnh = bhh[1024 + col];
    #pragma unroll
    for (int m = 0; m < 2; m++)
      #pragma unroll
      for (int j = 0; j < 4; j++){
        int row = rA0 + wm0 + m*16 + lj + j;
        float rg = sigm(aR[m][n][j] + brr);
        float zg = sigm(aZ[m][n][j] + bzz);
        float ng = tanhe(aNx[m][n][j] + bni + rg*(aNh[m][n][j] + bnh));
        float h  = bf2f(hbf[(size_t)row*512 + col]);
        hcell[(size_t)row*512 + col] = f2bf((1.0f - zg)*ng + zg*h);
      }
  }
}

// ---------------- residual projection: h_new = emb + h_cell @ res_W^T + res_b ----------------
// Round-8 form (grid (64,8)); round-9 col-split measured neutral-negative.
__global__ __launch_bounds__(256) void res_kernel(
    const unsigned short* __restrict__ hcell, const unsigned short* __restrict__ Wres,
    const float* __restrict__ res_b, const unsigned short* __restrict__ emb,
    unsigned short* __restrict__ hbf){
  __shared__ unsigned short As[8192];
  __shared__ unsigned short Bs[4096];
  int tid = threadIdx.x, lane = tid & 63, wid = tid >> 6, wm0 = wid*32;
  int rA0 = blockIdx.x*128, d0 = blockIdx.y*64;

  f32x4 acc[2][4]; zero24(acc);
  kloopS(hcell + (size_t)rA0*512, Wres + (size_t)d0*512, As, Bs, tid, wm0, lane, acc);

  int lr = lane & 15, lj = (lane >> 4)*4;
  #pragma unroll
  for (int m = 0; m < 2; m++)
    #pragma unroll
    for (int n = 0; n < 4; n++){
      int col = d0 + n*16 + lr;
      float bb = res_b[col];
      #pragma unroll
      for (int j = 0; j < 4; j++){
        int row = rA0 + wm0 + m*16 + lj + j;
        float v = acc[m][n][j] + bb + bf2f(emb[(size_t)row*512 + col]);
        hbf[(size_t)row*512 + col] = f2bf(v);
      }
    }
}

// ---------------- generic: C = A(Mx512) @ B^T + bias, out ld=Nld ----------------
template<bool BF16OUT>
__global__ __launch_bounds__(256) void gemm_bias_kernel(
    const unsigned short* __restrict__ A, const unsigned short* __restrict__ B,
    const float* __restrict__ bias, float* __restrict__ Cf,
    unsigned short* __restrict__ Cb, int Nld){
  __shared__ unsigned short As[8192];
  __shared__ unsigned short Bs[4096];
  int tid = threadIdx.x, lane = tid & 63, wid = tid >> 6, wm0 = wid*32;
  int rA0 = blockIdx.x*128, rB0 = blockIdx.y*64;

  f32x4 acc[2][4]; zero24(acc);
  kloopS(A + (size_t)rA0*512, B + (size_t)rB0*512, As, Bs, tid, wm0, lane, acc);

  int lr = lane & 15, lj = (lane >> 4)*4;
  #pragma unroll
  for (int m = 0; m < 2; m++)
    #pragma unroll
    for (int n = 0; n < 4; n++){
      int col = rB0 + n*16 + lr;
      float bb = bias[col];
      #pragma unroll
      for (int j = 0; j < 4; j++){
        int row = rA0 + wm0 + m*16 + lj + j;
        float v = acc[m][n][j] + bb;
        if (BF16OUT) Cb[(size_t)row*Nld + col] = f2bf(v);
        else         Cf[(size_t)row*Nld + col] = v;
      }
    }
}

// ---------------- decoder elementwise: hy (bf16) ----------------
DEV void bf8ld(const unsigned short* p, float* o){
  // 1 VALU per value: lo = u<<16, hi = u & 0xffff0000
  uint4 u = *reinterpret_cast<const uint4*>(p);
  union { uint32_t w; float f; } v;
  v.w = u.x << 16;          o[0] = v.f;
  v.w = u.x & 0xffff0000u;  o[1] = v.f;
  v.w = u.y << 16;          o[2] = v.f;
  v.w = u.y & 0xffff0000u;  o[3] = v.f;
  v.w = u.z << 16;          o[4] = v.f;
  v.w = u.z & 0xffff0000u;  o[5] = v.f;
  v.w = u.w << 16;          o[6] = v.f;
  v.w = u.w & 0xffff0000u;  o[7] = v.f;
}

__global__ __launch_bounds__(256) void hy_kernel(const unsigned short* __restrict__ gxd,
    const unsigned short* __restrict__ ghd, const unsigned short* __restrict__ hb,
    unsigned short* __restrict__ hy){
  int gid = blockIdx.x*256 + threadIdx.x;    // 8 chunks per thread, 2048 blocks
  #pragma unroll 1
  for (int it = 0; it < 8; it++, gid += 2048*256){
    int r = gid >> 6, dg = gid & 63;
    int n = r >> 3, sy = r & 7, c = n & 63, mpe = c*8 + sy;
    int d = dg*8;
    const unsigned short* gx = gxd + (size_t)mpe*1536 + d;
    const unsigned short* gh = ghd + (size_t)n*1536 + d;
    const unsigned short* hh = hb + (size_t)n*512 + d;
    float xr[8], xz[8], xn[8], hr[8], hz[8], hn[8], h[8];
    bf8ld(gx, xr); bf8ld(gx + 512, xz); bf8ld(gx + 1024, xn);
    bf8ld(gh, hr); bf8ld(gh + 512, hz); bf8ld(gh + 1024, hn); bf8ld(hh, h);
    unsigned short w[8];
    #pragma unroll
    for (int j = 0; j < 8; j++){
      float rg = sigm(xr[j] + hr[j]);
      float zg = sigm(xz[j] + hz[j]);
      float ng = tanhe(xn[j] + rg*hn[j]);
      w[j] = f2bf((1.0f - zg)*ng + zg*h[j]);
    }
    *reinterpret_cast<uint4*>(hy + (size_t)r*512 + d) =
        *reinterpret_cast<const uint4*>(w);
  }
}

// ---------------- decoder predict GEMM: out = hy @ predW^T + ... ----------------
__global__ __launch_bounds__(256) void pred_kernel(
    const unsigned short* __restrict__ hy, const unsigned short* __restrict__ predW,
    const float* __restrict__ predb, const float* __restrict__ x,
    float* __restrict__ out){
  __shared__ unsigned short As[8192];
  __shared__ unsigned short Bs[4096];
  int tid = threadIdx.x, lane = tid & 63, wid = tid >> 6, wm0 = wid*32;
  int rA0 = blockIdx.x*128;

  f32x4 acc[2][4]; zero24(acc);
  kloopS(hy + (size_t)rA0*512, predW, As, Bs, tid, wm0, lane, acc);

  int lr = lane & 15, lj = (lane >> 4)*4;
  #pragma unroll
  for (int n = 0; n < 4; n++){
    int s = n*16 + lr;
    float bb = predb[s];
    #pragma unroll
    for (int m = 0; m < 2; m++)
      #pragma unroll
      for (int j = 0; j < 4; j++){
        int r = rA0 + wm0 + m*16 + lj + j;
        int nn = r >> 3, sy = r & 7, b = nn >> 6, c = nn & 63;
        out[(size_t)b*32768 + (size_t)(sy*64 + s)*64 + c] =
            acc[m][n][j] + bb + x[(size_t)b*65536 + 65472 + c];
      }
  }
}

// ---------------- host ----------------
extern "C" void kernel_launch(void* const* d_in, const int* in_sizes, int n_in,
                              void* d_out, int out_size, void* d_ws, size_t ws_size,
                              hipStream_t stream){
  (void)in_sizes; (void)n_in; (void)out_size;
  const float* x     = (const float*)d_in[0];
  const float* Wemb  = (const float*)d_in[1];
  const float* bemb  = (const float*)d_in[2];
  const float* cWih  = (const float*)d_in[3];
  const float* cWhh  = (const float*)d_in[4];
  const float* cbih  = (const float*)d_in[5];
  const float* cbhh  = (const float*)d_in[6];
  const float* gWih  = (const float*)d_in[7];
  const float* gWhh  = (const float*)d_in[8];
  const float* gbih  = (const float*)d_in[9];
  const float* gbhh  = (const float*)d_in[10];
  const float* resW  = (const float*)d_in[11];
  const float* resb  = (const float*)d_in[12];
  const float* pos   = (const float*)d_in[13];
  const float* chan  = (const float*)d_in[14];
  const float* predW = (const float*)d_in[15];
  const float* predb = (const float*)d_in[16];
  float* out = (float*)d_out;

  uint8_t* ws = (uint8_t*)d_ws;
  size_t o = 0;
  auto take = [&](size_t bytes){ uint8_t* p = ws + o; o += (bytes + 255) & ~(size_t)255; return p; };
  unsigned short* wb_cWih  = (unsigned short*)take(786432*2);
  unsigned short* wb_cWhh  = (unsigned short*)take(786432*2);
  unsigned short* wb_gWih  = (unsigned short*)take(786432*2);
  unsigned short* wb_gWhh  = (unsigned short*)take(786432*2);
  unsigned short* wb_resW  = (unsigned short*)take(262144*2);
  unsigned short* wb_predW = (unsigned short*)take(32768*2);
  unsigned short* wb_Wemb  = (unsigned short*)take(32768*2);
  unsigned short* pe_bf    = (unsigned short*)take(262144*2);
  unsigned short* h_bf     = (unsigned short*)take(4194304*2);

  // union region: encoder {xs_all, hcell, emb} / decoder {ghd(bf16), gxd(bf16), hy(bf16)}
  uint8_t* U = ws + o;
  unsigned short* xs_all = (unsigned short*)(U);
  unsigned short* hcell  = (unsigned short*)(U + 16777216);
  unsigned short* emb    = (unsigned short*)(U + 25165824);
  unsigned short* ghd    = (unsigned short*)(U);                 // 8192*1536*2 = 25165824
  unsigned short* gxd    = (unsigned short*)(U + 25165824);      // 512*1536*2  = 1572864
  unsigned short* hy     = (unsigned short*)(U + 28311552);      // 65536*512*2 = 67108864

  bool big = ws_size >= o + (size_t)25165824 + (size_t)16*8388608;
  size_t zs = big ? 4194304 : 0;

  cvt_all_kernel<<<3392, 256, 0, stream>>>(cWih, cWhh, gWih, gWhh, resW, predW, Wemb,
      wb_cWih, wb_cWhh, wb_gWih, wb_gWhh, wb_resW, wb_predW, wb_Wemb);
  build_pe_kernel<<<1024, 256, 0, stream>>>(pos, chan, pe_bf);
  xs_kernel<<<dim3(16, 128), 256, 0, stream>>>(x, xs_all);
  hipMemsetAsync(h_bf, 0, (size_t)4194304*2, stream);

  if (big)
    embed_kernel<<<dim3(64, 8, 16), 256, 0, stream>>>(xs_all, wb_Wemb, bemb, emb, 0, zs);

  for (int t = 0; t < 16; t++){
    const unsigned short* emb_t = emb + (big ? (size_t)t*4194304 : 0);
    if (!big)
      embed_kernel<<<dim3(64, 8, 1), 256, 0, stream>>>(xs_all, wb_Wemb, bemb,
                                                       (unsigned short*)emb_t, t, 0);
    gates_kernel<<<1024, 256, 0, stream>>>(emb_t, h_bf, wb_cWih, wb_cWhh,
                                           cbih, cbhh, hcell);
    res_kernel<<<dim3(64, 8), 256, 0, stream>>>(hcell, wb_resW, resb, emb_t, h_bf);
  }

  // decoder: ghd(bf16) = hn @ gru_Whh^T + gbhh ; gxd(bf16) = pe @ gru_Wih^T + gbih
  gemm_bias_kernel<true><<<dim3(64, 24), 256, 0, stream>>>(h_bf, wb_gWhh, gbhh,
                                                           nullptr, ghd, 1536);
  gemm_bias_kernel<true><<<dim3(4, 24), 256, 0, stream>>>(pe_bf, wb_gWih, gbih,
                                                          nullptr, gxd, 1536);
  hy_kernel<<<2048, 256, 0, stream>>>(gxd, ghd, h_bf, hy);
  pred_kernel<<<512, 256, 0, stream>>>(hy, wb_predW, predb, x, out);
}